// Round 4
// baseline (837.935 us; speedup 1.0000x reference)
//
#include <hip/hip_runtime.h>
#include <math.h>

#define BATCH  131072
#define NCLASS 1000
#define FDIM   512
#define CHUNKS 4
#define NGATH  (NCLASS * CHUNKS)   // 4000 gather blocks
#define NTILE  136                 // 16*17/2 upper-tri 64x64 tiles
#define K3BLK  (NGATH + NTILE)

// ws layout (bytes):
//  0        int   counts[1024]
//  4096     int   cursor0[1024]   zero-based scatter tickets
//  8192     float accs[2]         {sum_dist_init, sum_hinge}
//  8200     int   done            K4 ticket
//  8704     int   arrive[1024]    K3 per-class finalize tickets
//  16384    int   offsets[1024]   exclusive scan of counts
//  20480    float norms_init[1024]
//  24576    float norms_new[1024]
//  28672    int   perm[131072]    (512 KB)
//  557056   float pbuf[4][1000][512]  (8.19 MB)
//  8749056  float wsM[1000][512]      (aligned copy of new centers)
// memset covers [0, 12800): counts, cursor0, accs, done, arrive.

// ---- K1: bincount (blocks 0..127) + init-center row norms (all 1000) ------
__global__ __launch_bounds__(256)
void k1_prep(const float* __restrict__ center, const int* __restrict__ labels,
             float* __restrict__ norms_init, int* __restrict__ counts) {
    const int b = blockIdx.x, t = threadIdx.x;
    __shared__ float w4[4];
    if (b < BATCH / 1024) {
        int4 l = ((const int4*)labels)[b * 256 + t];
        atomicAdd(&counts[l.x], 1);
        atomicAdd(&counts[l.y], 1);
        atomicAdd(&counts[l.z], 1);
        atomicAdd(&counts[l.w], 1);
    }
    float2 v = ((const float2*)(center + (size_t)b * FDIM))[t];
    float s = v.x * v.x + v.y * v.y;
    for (int off = 32; off > 0; off >>= 1) s += __shfl_down(s, off, 64);
    if ((t & 63) == 0) w4[t >> 6] = s;
    __syncthreads();
    if (t == 0) norms_init[b] = (w4[0] + w4[1]) + (w4[2] + w4[3]);
}

// ---- K2: redundant per-block LDS scan of counts + scatter ------------------
__global__ __launch_bounds__(256)
void k2_scan_scatter(const int* __restrict__ labels, const int* __restrict__ counts,
                     int* __restrict__ cursor0, int* __restrict__ perm,
                     int* __restrict__ g_offsets) {
    __shared__ int sA[1024];
    __shared__ int sB[1024];
    const int b = blockIdx.x, t = threadIdx.x;
    for (int i = t; i < 1024; i += 256) sA[i] = counts[i];
    __syncthreads();
    int* cur = sA;
    int* nxt = sB;
    for (int off = 1; off < 1024; off <<= 1) {
        for (int i = t; i < 1024; i += 256) {
            int v = cur[i];
            if (i >= off) v += cur[i - off];
            nxt[i] = v;
        }
        __syncthreads();
        int* tmp = cur; cur = nxt; nxt = tmp;
    }
    int* offp = nxt;                       // free buffer; cur = inclusive scan
    for (int i = t; i < 1024; i += 256) offp[i] = i ? cur[i - 1] : 0;
    __syncthreads();
    if (b == 0)
        for (int i = t; i < 1024; i += 256) g_offsets[i] = offp[i];
    const int gid = b * 256 + t;
    int4 l = ((const int4*)labels)[gid];
    const int r = gid * 4;
    perm[offp[l.x] + atomicAdd(&cursor0[l.x], 1)] = r + 0;
    perm[offp[l.y] + atomicAdd(&cursor0[l.y], 1)] = r + 1;
    perm[offp[l.z] + atomicAdd(&cursor0[l.z], 1)] = r + 2;
    perm[offp[l.w] + atomicAdd(&cursor0[l.w], 1)] = r + 3;
}

// ---- shared dist tile: 64x64 GEMM tile + hinge/dist partial ---------------
template <int MODE>
__device__ __forceinline__ void dist_tile(const float* __restrict__ M,
                                          const float* __restrict__ norms,
                                          float th, int by, int bx,
                                          float (*As)[36], float (*Bs)[36],
                                          float* red, float* accs) {
    const int tid = threadIdx.x;
    const int bi = by * 64, bj = bx * 64;
    const int tx = tid & 15, ty = tid >> 4;
    float acc[4][4];
#pragma unroll
    for (int ii = 0; ii < 4; ++ii)
#pragma unroll
        for (int jj = 0; jj < 4; ++jj) acc[ii][jj] = 0.0f;

    for (int k0 = 0; k0 < FDIM; k0 += 32) {
        __syncthreads();
#pragma unroll
        for (int l = tid; l < 512; l += 256) {
            const int rr = l >> 3, k4 = l & 7;
            const int gi = bi + rr, gj = bj + rr;
            const float4 z = make_float4(0.f, 0.f, 0.f, 0.f);
            float4 av = (gi < NCLASS) ? ((const float4*)(M + (size_t)gi * FDIM + k0))[k4] : z;
            float4 bv = (gj < NCLASS) ? ((const float4*)(M + (size_t)gj * FDIM + k0))[k4] : z;
            *(float4*)&As[rr][k4 * 4] = av;
            *(float4*)&Bs[rr][k4 * 4] = bv;
        }
        __syncthreads();
#pragma unroll
        for (int kk = 0; kk < 32; kk += 4) {
            float4 a[4], b[4];
#pragma unroll
            for (int ii = 0; ii < 4; ++ii) a[ii] = *(const float4*)&As[ty * 4 + ii][kk];
#pragma unroll
            for (int jj = 0; jj < 4; ++jj) b[jj] = *(const float4*)&Bs[tx * 4 + jj][kk];
#pragma unroll
            for (int ii = 0; ii < 4; ++ii)
#pragma unroll
                for (int jj = 0; jj < 4; ++jj) {
                    acc[ii][jj] += a[ii].x * b[jj].x + a[ii].y * b[jj].y +
                                   a[ii].z * b[jj].z + a[ii].w * b[jj].w;
                }
        }
    }

    float local = 0.0f;
#pragma unroll
    for (int ii = 0; ii < 4; ++ii)
#pragma unroll
        for (int jj = 0; jj < 4; ++jj) {
            const int gi = bi + ty * 4 + ii;
            const int gj = bj + tx * 4 + jj;
            if (gi < NCLASS && gj < NCLASS && gj > gi) {
                float d2 = norms[gi] + norms[gj] - 2.0f * acc[ii][jj];
                d2 = fmaxf(d2, 0.0f);
                float dst = (d2 > 0.0f) ? sqrtf(d2) : 0.0f;
                if (MODE == 1) {
                    if (dst < th) local += th - dst;
                } else {
                    local += dst;
                }
            }
        }

    __syncthreads();
    red[tid] = local;
    __syncthreads();
    for (int s = 128; s > 0; s >>= 1) {
        if (tid < s) red[tid] += red[tid + s];
        __syncthreads();
    }
    if (tid == 0) atomicAdd(&accs[MODE], red[0]);
}

// ---- K3: class gather + dist0 tiles + ticket-fused finalize ----------------
__global__ __launch_bounds__(256)
void k3_gather(const float* __restrict__ features,
               const float* __restrict__ center,
               const int* __restrict__ g_offsets,
               const int* __restrict__ counts,
               const int* __restrict__ perm,
               float* __restrict__ pbuf,
               int* __restrict__ arrive,
               const float* __restrict__ norms_init,
               float* __restrict__ accs,
               float* __restrict__ out_center,
               float* __restrict__ wsM,
               float* __restrict__ norms_new) {
    __shared__ float As[64][36];
    __shared__ float Bs[64][36];
    __shared__ float red[256];
    __shared__ int   lp[256];
    __shared__ float w4[4];
    __shared__ int   flag;
    const int b = blockIdx.x, t = threadIdx.x;

    if (b >= NGATH) {                       // dist0 tiles, run concurrently
        int idx = b - NGATH;
        int by = 0;
        while (idx >= 16 - by) { idx -= 16 - by; ++by; }
        dist_tile<0>(center, norms_init, 0.0f, by, by + idx, As, Bs, red, accs);
        return;
    }

    const int c = b % NCLASS, q = b / NCLASS;
    const int beg = g_offsets[c];
    const int n   = counts[c];
    const int per = (n + CHUNKS - 1) / CHUNKS;
    const int s0  = q * per;
    const int e0  = min(n, s0 + per);
    const float2* fp = (const float2*)features;
    float2 acc = make_float2(0.f, 0.f);
    for (int base = s0; base < e0; base += 256) {
        const int mm = min(256, e0 - base);
        __syncthreads();
        if (t < mm) lp[t] = perm[beg + base + t];
        __syncthreads();
        int r = 0;
        for (; r + 8 <= mm; r += 8) {
            int i0 = lp[r + 0], i1 = lp[r + 1], i2 = lp[r + 2], i3 = lp[r + 3];
            int i4 = lp[r + 4], i5 = lp[r + 5], i6 = lp[r + 6], i7 = lp[r + 7];
            float2 v0 = fp[(size_t)i0 * 256 + t];
            float2 v1 = fp[(size_t)i1 * 256 + t];
            float2 v2 = fp[(size_t)i2 * 256 + t];
            float2 v3 = fp[(size_t)i3 * 256 + t];
            float2 v4 = fp[(size_t)i4 * 256 + t];
            float2 v5 = fp[(size_t)i5 * 256 + t];
            float2 v6 = fp[(size_t)i6 * 256 + t];
            float2 v7 = fp[(size_t)i7 * 256 + t];
            acc.x += ((v0.x + v1.x) + (v2.x + v3.x)) + ((v4.x + v5.x) + (v6.x + v7.x));
            acc.y += ((v0.y + v1.y) + (v2.y + v3.y)) + ((v4.y + v5.y) + (v6.y + v7.y));
        }
        for (; r < mm; ++r) {
            float2 v = fp[(size_t)lp[r] * 256 + t];
            acc.x += v.x; acc.y += v.y;
        }
    }
    ((float2*)(pbuf + ((size_t)q * NCLASS + c) * FDIM))[t] = acc;

    // last-arriving chunk of this class finalizes it
    __threadfence();
    __syncthreads();
    if (t == 0) flag = (atomicAdd(&arrive[c], 1) == CHUNKS - 1);
    __syncthreads();
    if (!flag) return;
    __threadfence();

    float2 p0 = ((const float2*)(pbuf + ((size_t)0 * NCLASS + c) * FDIM))[t];
    float2 p1 = ((const float2*)(pbuf + ((size_t)1 * NCLASS + c) * FDIM))[t];
    float2 p2 = ((const float2*)(pbuf + ((size_t)2 * NCLASS + c) * FDIM))[t];
    float2 p3 = ((const float2*)(pbuf + ((size_t)3 * NCLASS + c) * FDIM))[t];
    float2 cc = ((const float2*)(center + (size_t)c * FDIM))[t];
    const float invn = 1.0f / fmaxf((float)n, 1.0f);
    float2 nc;
    nc.x = (cc.x + ((p0.x + p1.x) + (p2.x + p3.x))) * invn;
    nc.y = (cc.y + ((p0.y + p1.y) + (p2.y + p3.y))) * invn;
    float* o = out_center + (size_t)c * FDIM + t * 2;   // base is +1 float: scalar stores
    o[0] = nc.x; o[1] = nc.y;
    ((float2*)(wsM + (size_t)c * FDIM))[t] = nc;
    float s = nc.x * nc.x + nc.y * nc.y;
    for (int off = 32; off > 0; off >>= 1) s += __shfl_down(s, off, 64);
    if ((t & 63) == 0) w4[t >> 6] = s;
    __syncthreads();
    if (t == 0) norms_new[c] = (w4[0] + w4[1]) + (w4[2] + w4[3]);
}

// ---- K4: dist1 tiles + ticket loss finalize --------------------------------
__global__ __launch_bounds__(256)
void k4_dist1(const float* __restrict__ wsM, const float* __restrict__ norms_new,
              float* __restrict__ accs, int* __restrict__ done,
              float* __restrict__ out0) {
    __shared__ float As[64][36];
    __shared__ float Bs[64][36];
    __shared__ float red[256];
    int idx = blockIdx.x;
    int by = 0;
    while (idx >= 16 - by) { idx -= 16 - by; ++by; }
    const float th = 6.0f * accs[0] * 1e-6f;
    dist_tile<1>(wsM, norms_new, th, by, by + idx, As, Bs, red, accs);
    if (threadIdx.x == 0) {
        __threadfence();
        if (atomicAdd(done, 1) == NTILE - 1) {
            __threadfence();
            const float l1 = atomicAdd(&accs[1], 0.0f);
            const double thd = 6.0 * (double)accs[0] * 1e-6;
            out0[0] = (float)((2.0 * (double)l1 + (double)NCLASS * thd) * 1e-6);
        }
    }
}

extern "C" void kernel_launch(void* const* d_in, const int* in_sizes, int n_in,
                              void* d_out, int out_size, void* d_ws, size_t ws_size,
                              hipStream_t stream) {
    const float* features = (const float*)d_in[0];
    const float* center   = (const float*)d_in[1];
    const int*   labels   = (const int*)d_in[2];
    float* out = (float*)d_out;
    char*  ws  = (char*)d_ws;

    int*   counts     = (int*)(ws + 0);
    int*   cursor0    = (int*)(ws + 4096);
    float* accs       = (float*)(ws + 8192);
    int*   done       = (int*)(ws + 8200);
    int*   arrive     = (int*)(ws + 8704);
    int*   g_offsets  = (int*)(ws + 16384);
    float* norms_init = (float*)(ws + 20480);
    float* norms_new  = (float*)(ws + 24576);
    int*   perm       = (int*)(ws + 28672);
    float* pbuf       = (float*)(ws + 557056);
    float* wsM        = (float*)(ws + 8749056);

    hipMemsetAsync(ws, 0, 12800, stream);
    k1_prep<<<NCLASS, 256, 0, stream>>>(center, labels, norms_init, counts);
    k2_scan_scatter<<<BATCH / 1024, 256, 0, stream>>>(labels, counts, cursor0, perm,
                                                      g_offsets);
    k3_gather<<<K3BLK, 256, 0, stream>>>(features, center, g_offsets, counts, perm,
                                         pbuf, arrive, norms_init, accs, out + 1,
                                         wsM, norms_new);
    k4_dist1<<<NTILE, 256, 0, stream>>>(wsM, norms_new, accs, done, out);
}

// Round 5
// 211.733 us; speedup vs baseline: 3.9575x; 3.9575x over previous
//
#include <hip/hip_runtime.h>
#include <math.h>

#define BATCH  131072
#define NCLASS 1000
#define FDIM   512
#define CHUNKS 4
#define NTILE  136                 // 16*17/2 upper-tri 64x64 tiles

typedef float f32x4 __attribute__((ext_vector_type(4)));

// ws layout (bytes):
//  0        int   counts[1024]
//  4096     int   cursor0[1024]   zero-based scatter tickets
//  8192     float accs[2]         {sum_dist_init, sum_hinge}
//  8200     int   done            K5 ticket
//  16384    int   offsets[1024]   exclusive scan of counts
//  20480    float norms_init[1024]
//  24576    float norms_new[1024]
//  28672    int   perm[131072]    (512 KB)
//  557056   float pbuf[4][1000][512]  (8.19 MB)
//  8749056  float wsM[1000][512]      (aligned copy of new centers)
// memset covers [0, 12800).

// ---- shared dist tile: 64x64 GEMM tile + hinge/dist partial ----------------
template <int MODE>
__device__ __forceinline__ void dist_tile(const float* __restrict__ M,
                                          const float* __restrict__ norms,
                                          float th, int by, int bx,
                                          float (*As)[36], float (*Bs)[36],
                                          float* red, float* accs) {
    const int tid = threadIdx.x;
    const int bi = by * 64, bj = bx * 64;
    const int tx = tid & 15, ty = tid >> 4;
    float acc[4][4];
#pragma unroll
    for (int ii = 0; ii < 4; ++ii)
#pragma unroll
        for (int jj = 0; jj < 4; ++jj) acc[ii][jj] = 0.0f;

    for (int k0 = 0; k0 < FDIM; k0 += 32) {
        __syncthreads();
#pragma unroll
        for (int l = tid; l < 512; l += 256) {
            const int rr = l >> 3, k4 = l & 7;
            const int gi = bi + rr, gj = bj + rr;
            const float4 z = make_float4(0.f, 0.f, 0.f, 0.f);
            float4 av = (gi < NCLASS) ? ((const float4*)(M + (size_t)gi * FDIM + k0))[k4] : z;
            float4 bv = (gj < NCLASS) ? ((const float4*)(M + (size_t)gj * FDIM + k0))[k4] : z;
            *(float4*)&As[rr][k4 * 4] = av;
            *(float4*)&Bs[rr][k4 * 4] = bv;
        }
        __syncthreads();
#pragma unroll
        for (int kk = 0; kk < 32; kk += 4) {
            float4 a[4], b[4];
#pragma unroll
            for (int ii = 0; ii < 4; ++ii) a[ii] = *(const float4*)&As[ty * 4 + ii][kk];
#pragma unroll
            for (int jj = 0; jj < 4; ++jj) b[jj] = *(const float4*)&Bs[tx * 4 + jj][kk];
#pragma unroll
            for (int ii = 0; ii < 4; ++ii)
#pragma unroll
                for (int jj = 0; jj < 4; ++jj) {
                    acc[ii][jj] += a[ii].x * b[jj].x + a[ii].y * b[jj].y +
                                   a[ii].z * b[jj].z + a[ii].w * b[jj].w;
                }
        }
    }

    float local = 0.0f;
#pragma unroll
    for (int ii = 0; ii < 4; ++ii)
#pragma unroll
        for (int jj = 0; jj < 4; ++jj) {
            const int gi = bi + ty * 4 + ii;
            const int gj = bj + tx * 4 + jj;
            if (gi < NCLASS && gj < NCLASS && gj > gi) {
                float d2 = norms[gi] + norms[gj] - 2.0f * acc[ii][jj];
                d2 = fmaxf(d2, 0.0f);
                float dst = (d2 > 0.0f) ? sqrtf(d2) : 0.0f;
                if (MODE == 1) {
                    if (dst < th) local += th - dst;
                } else {
                    local += dst;
                }
            }
        }

    __syncthreads();
    red[tid] = local;
    __syncthreads();
    for (int s = 128; s > 0; s >>= 1) {
        if (tid < s) red[tid] += red[tid + s];
        __syncthreads();
    }
    if (tid == 0) atomicAdd(&accs[MODE], red[0]);
}

// ---- K1: bincount (blocks 0..127) + init-center row norms (all 1000) ------
__global__ __launch_bounds__(256)
void k1_prep(const float* __restrict__ center, const int* __restrict__ labels,
             float* __restrict__ norms_init, int* __restrict__ counts) {
    const int b = blockIdx.x, t = threadIdx.x;
    __shared__ float w4[4];
    if (b < BATCH / 1024) {
        int4 l = ((const int4*)labels)[b * 256 + t];
        atomicAdd(&counts[l.x], 1);
        atomicAdd(&counts[l.y], 1);
        atomicAdd(&counts[l.z], 1);
        atomicAdd(&counts[l.w], 1);
    }
    float2 v = ((const float2*)(center + (size_t)b * FDIM))[t];
    float s = v.x * v.x + v.y * v.y;
    for (int off = 32; off > 0; off >>= 1) s += __shfl_down(s, off, 64);
    if ((t & 63) == 0) w4[t >> 6] = s;
    __syncthreads();
    if (t == 0) norms_init[b] = (w4[0] + w4[1]) + (w4[2] + w4[3]);
}

// ---- K2: blocks 0..127 scan+scatter; blocks 128..263 dist0 tiles -----------
__global__ __launch_bounds__(256)
void k2_scan_scatter_dist0(const int* __restrict__ labels,
                           const int* __restrict__ counts,
                           int* __restrict__ cursor0, int* __restrict__ perm,
                           int* __restrict__ g_offsets,
                           const float* __restrict__ center,
                           const float* __restrict__ norms_init,
                           float* __restrict__ accs) {
    __shared__ float As[64][36];
    __shared__ float Bs[64][36];
    __shared__ float red[256];
    const int b = blockIdx.x, t = threadIdx.x;

    if (b >= BATCH / 1024) {                  // 136 dist0 tiles
        int idx = b - BATCH / 1024;
        int by = 0;
        while (idx >= 16 - by) { idx -= 16 - by; ++by; }
        dist_tile<0>(center, norms_init, 0.0f, by, by + idx, As, Bs, red, accs);
        return;
    }

    int* sA = (int*)&As[0][0];                // reuse LDS: 1024 ints
    int* sB = (int*)&Bs[0][0];
    for (int i = t; i < 1024; i += 256) sA[i] = counts[i];
    __syncthreads();
    int* cur = sA;
    int* nxt = sB;
    for (int off = 1; off < 1024; off <<= 1) {
        for (int i = t; i < 1024; i += 256) {
            int v = cur[i];
            if (i >= off) v += cur[i - off];
            nxt[i] = v;
        }
        __syncthreads();
        int* tmp = cur; cur = nxt; nxt = tmp;
    }
    int* offp = nxt;                          // free buffer; cur = inclusive
    for (int i = t; i < 1024; i += 256) offp[i] = i ? cur[i - 1] : 0;
    __syncthreads();
    if (b == 0)
        for (int i = t; i < 1024; i += 256) g_offsets[i] = offp[i];
    const int gid = b * 256 + t;
    int4 l = ((const int4*)labels)[gid];
    const int r = gid * 4;
    perm[offp[l.x] + atomicAdd(&cursor0[l.x], 1)] = r + 0;
    perm[offp[l.y] + atomicAdd(&cursor0[l.y], 1)] = r + 1;
    perm[offp[l.z] + atomicAdd(&cursor0[l.z], 1)] = r + 2;
    perm[offp[l.w] + atomicAdd(&cursor0[l.w], 1)] = r + 3;
}

// ---- K3: pure gather, grid (1000, CHUNKS) x 128, no fences -----------------
__global__ __launch_bounds__(128)
void k3_gather(const float* __restrict__ features,
               const int* __restrict__ g_offsets,
               const int* __restrict__ counts,
               const int* __restrict__ perm,
               float* __restrict__ pbuf) {
    const int c = blockIdx.x, q = blockIdx.y, t = threadIdx.x;
    const int beg = g_offsets[c], n = counts[c];
    const int per = (n + CHUNKS - 1) / CHUNKS;
    const int s0  = q * per;
    const int e0  = min(n, s0 + per);
    __shared__ int lp[128];
    f32x4 acc = {0.f, 0.f, 0.f, 0.f};
    for (int base = s0; base < e0; base += 128) {
        const int mm = min(128, e0 - base);
        __syncthreads();
        if (t < mm) lp[t] = perm[beg + base + t];
        __syncthreads();
        int r = 0;
        for (; r + 8 <= mm; r += 8) {
            const f32x4* p0 = (const f32x4*)(features + (size_t)lp[r + 0] * FDIM);
            const f32x4* p1 = (const f32x4*)(features + (size_t)lp[r + 1] * FDIM);
            const f32x4* p2 = (const f32x4*)(features + (size_t)lp[r + 2] * FDIM);
            const f32x4* p3 = (const f32x4*)(features + (size_t)lp[r + 3] * FDIM);
            const f32x4* p4 = (const f32x4*)(features + (size_t)lp[r + 4] * FDIM);
            const f32x4* p5 = (const f32x4*)(features + (size_t)lp[r + 5] * FDIM);
            const f32x4* p6 = (const f32x4*)(features + (size_t)lp[r + 6] * FDIM);
            const f32x4* p7 = (const f32x4*)(features + (size_t)lp[r + 7] * FDIM);
            f32x4 v0 = __builtin_nontemporal_load(p0 + t);
            f32x4 v1 = __builtin_nontemporal_load(p1 + t);
            f32x4 v2 = __builtin_nontemporal_load(p2 + t);
            f32x4 v3 = __builtin_nontemporal_load(p3 + t);
            f32x4 v4 = __builtin_nontemporal_load(p4 + t);
            f32x4 v5 = __builtin_nontemporal_load(p5 + t);
            f32x4 v6 = __builtin_nontemporal_load(p6 + t);
            f32x4 v7 = __builtin_nontemporal_load(p7 + t);
            acc += ((v0 + v1) + (v2 + v3)) + ((v4 + v5) + (v6 + v7));
        }
        for (; r < mm; ++r) {
            const f32x4* p = (const f32x4*)(features + (size_t)lp[r] * FDIM);
            acc += __builtin_nontemporal_load(p + t);
        }
    }
    ((f32x4*)(pbuf + ((size_t)q * NCLASS + c) * FDIM))[t] = acc;
}

// ---- K4: finalize new centers ----------------------------------------------
__global__ __launch_bounds__(128)
void k4_finalize(const float* __restrict__ center,
                 const float* __restrict__ pbuf,
                 const int* __restrict__ counts,
                 float* __restrict__ out_center,
                 float* __restrict__ wsM,
                 float* __restrict__ norms_new) {
    const int c = blockIdx.x, t = threadIdx.x;
    float4 p0 = ((const float4*)(pbuf + ((size_t)0 * NCLASS + c) * FDIM))[t];
    float4 p1 = ((const float4*)(pbuf + ((size_t)1 * NCLASS + c) * FDIM))[t];
    float4 p2 = ((const float4*)(pbuf + ((size_t)2 * NCLASS + c) * FDIM))[t];
    float4 p3 = ((const float4*)(pbuf + ((size_t)3 * NCLASS + c) * FDIM))[t];
    float4 cc = ((const float4*)(center + (size_t)c * FDIM))[t];
    const float invn = 1.0f / fmaxf((float)counts[c], 1.0f);
    float4 nc;
    nc.x = (cc.x + ((p0.x + p1.x) + (p2.x + p3.x))) * invn;
    nc.y = (cc.y + ((p0.y + p1.y) + (p2.y + p3.y))) * invn;
    nc.z = (cc.z + ((p0.z + p1.z) + (p2.z + p3.z))) * invn;
    nc.w = (cc.w + ((p0.w + p1.w) + (p2.w + p3.w))) * invn;
    float* o = out_center + (size_t)c * FDIM + t * 4;  // +1 float base: scalar stores
    o[0] = nc.x; o[1] = nc.y; o[2] = nc.z; o[3] = nc.w;
    ((float4*)(wsM + (size_t)c * FDIM))[t] = nc;
    float s = nc.x * nc.x + nc.y * nc.y + nc.z * nc.z + nc.w * nc.w;
    for (int off = 32; off > 0; off >>= 1) s += __shfl_down(s, off, 64);
    __shared__ float w2[2];
    if ((t & 63) == 0) w2[t >> 6] = s;
    __syncthreads();
    if (t == 0) norms_new[c] = w2[0] + w2[1];
}

// ---- K5: dist1 tiles + ticket loss finalize --------------------------------
__global__ __launch_bounds__(256)
void k5_dist1(const float* __restrict__ wsM, const float* __restrict__ norms_new,
              float* __restrict__ accs, int* __restrict__ done,
              float* __restrict__ out0) {
    __shared__ float As[64][36];
    __shared__ float Bs[64][36];
    __shared__ float red[256];
    int idx = blockIdx.x;
    int by = 0;
    while (idx >= 16 - by) { idx -= 16 - by; ++by; }
    const float th = 6.0f * accs[0] * 1e-6f;
    dist_tile<1>(wsM, norms_new, th, by, by + idx, As, Bs, red, accs);
    if (threadIdx.x == 0) {
        __threadfence();
        if (atomicAdd(done, 1) == NTILE - 1) {
            __threadfence();
            const float l1 = atomicAdd(&accs[1], 0.0f);
            const double thd = 6.0 * (double)accs[0] * 1e-6;
            out0[0] = (float)((2.0 * (double)l1 + (double)NCLASS * thd) * 1e-6);
        }
    }
}

extern "C" void kernel_launch(void* const* d_in, const int* in_sizes, int n_in,
                              void* d_out, int out_size, void* d_ws, size_t ws_size,
                              hipStream_t stream) {
    const float* features = (const float*)d_in[0];
    const float* center   = (const float*)d_in[1];
    const int*   labels   = (const int*)d_in[2];
    float* out = (float*)d_out;
    char*  ws  = (char*)d_ws;

    int*   counts     = (int*)(ws + 0);
    int*   cursor0    = (int*)(ws + 4096);
    float* accs       = (float*)(ws + 8192);
    int*   done       = (int*)(ws + 8200);
    int*   g_offsets  = (int*)(ws + 16384);
    float* norms_init = (float*)(ws + 20480);
    float* norms_new  = (float*)(ws + 24576);
    int*   perm       = (int*)(ws + 28672);
    float* pbuf       = (float*)(ws + 557056);
    float* wsM        = (float*)(ws + 8749056);

    hipMemsetAsync(ws, 0, 12800, stream);
    k1_prep<<<NCLASS, 256, 0, stream>>>(center, labels, norms_init, counts);
    k2_scan_scatter_dist0<<<BATCH / 1024 + NTILE, 256, 0, stream>>>(
        labels, counts, cursor0, perm, g_offsets, center, norms_init, accs);
    k3_gather<<<dim3(NCLASS, CHUNKS), 128, 0, stream>>>(features, g_offsets, counts,
                                                        perm, pbuf);
    k4_finalize<<<NCLASS, 128, 0, stream>>>(center, pbuf, counts, out + 1, wsM,
                                            norms_new);
    k5_dist1<<<NTILE, 256, 0, stream>>>(wsM, norms_new, accs, done, out);
}